// Round 1
// baseline (610.276 us; speedup 1.0000x reference)
//
#include <hip/hip_runtime.h>
#include <cstdint>
#include <cstddef>

#define ALPHA 0.2f
// N=8192, Fin=512, Fout=256 hard-coded per problem instance.

typedef __attribute__((ext_vector_type(8)))  short short8;   // 8 bf16 (4 VGPRs)
typedef __attribute__((ext_vector_type(16))) float f32x16;   // 32x32 MFMA acc

static __device__ __forceinline__ unsigned short f2bf(float x) {
  union { float f; unsigned u; } c; c.f = x;
  unsigned u = c.u;
  unsigned r = (u + 0x7FFFu + ((u >> 16) & 1u)) >> 16;  // RNE
  return (unsigned short)r;
}
static __device__ __forceinline__ float bf2f(unsigned short b) {
  union { unsigned u; float f; } c; c.u = ((unsigned)b) << 16;
  return c.f;
}

// ---------------- Kernel A: Wh = h @ W  (fp32, 8192x512 * 512x256) ----------
// BM=128, BN=64, BK=32, 256 threads, 8x4 per thread. grid 64*4=256 blocks.
__global__ __launch_bounds__(256, 2) void gemm1(const float* __restrict__ h,
                                                const float* __restrict__ W,
                                                float* __restrict__ Wh) {
  __shared__ float As[32][132];  // [k][m], padded to 132 floats (528B, 16B-mult)
  __shared__ float Bs[32][64];   // [k][n]
  const int t = threadIdx.x;
  const int bid = blockIdx.x;
  const int nb = bid & 3, mb = bid >> 2;
  const int m0 = mb * 128, n0 = nb * 64;
  const int ty = t >> 4, tx = t & 15;   // rows ty*8.., cols tx*4..
  float acc[8][4];
#pragma unroll
  for (int i = 0; i < 8; i++)
#pragma unroll
    for (int j = 0; j < 4; j++) acc[i][j] = 0.f;

  for (int k0 = 0; k0 < 512; k0 += 32) {
#pragma unroll
    for (int c = 0; c < 4; c++) {                 // stage A with transpose
      int m = c * 32 + (t >> 3);
      int kq = (t & 7) * 4;
      float4 v = *(const float4*)&h[(size_t)(m0 + m) * 512 + k0 + kq];
      As[kq + 0][m] = v.x; As[kq + 1][m] = v.y;
      As[kq + 2][m] = v.z; As[kq + 3][m] = v.w;
    }
#pragma unroll
    for (int c = 0; c < 2; c++) {                 // stage B
      int k = c * 16 + (t >> 4);
      int n = (t & 15) * 4;
      *(float4*)&Bs[k][n] = *(const float4*)&W[(size_t)(k0 + k) * 256 + n0 + n];
    }
    __syncthreads();
#pragma unroll
    for (int k = 0; k < 32; k++) {
      float4 a0 = *(float4*)&As[k][ty * 8];
      float4 a1 = *(float4*)&As[k][ty * 8 + 4];
      float4 b  = *(float4*)&Bs[k][tx * 4];
      float av[8] = {a0.x, a0.y, a0.z, a0.w, a1.x, a1.y, a1.z, a1.w};
      float bv[4] = {b.x, b.y, b.z, b.w};
#pragma unroll
      for (int i = 0; i < 8; i++)
#pragma unroll
        for (int j = 0; j < 4; j++) acc[i][j] = fmaf(av[i], bv[j], acc[i][j]);
    }
    __syncthreads();
  }
#pragma unroll
  for (int i = 0; i < 8; i++) {
    float4 v = {acc[i][0], acc[i][1], acc[i][2], acc[i][3]};
    *(float4*)&Wh[(size_t)(m0 + ty * 8 + i) * 256 + n0 + tx * 4] = v;
  }
}

// ------------- Kernel B: per-row f1,f2, u/v pack, and bf16 transpose --------
// one wave per row; grid 2048 x 256
__global__ __launch_bounds__(256) void rowstats(const float* __restrict__ Wh,
                                                const float* __restrict__ a,
                                                float* __restrict__ f1,
                                                float* __restrict__ f2,
                                                unsigned* __restrict__ uvpack,
                                                unsigned short* __restrict__ WhT) {
  const int t = threadIdx.x;
  const int w = t >> 6, lane = t & 63;
  const int i = blockIdx.x * 4 + w;
  float4 wv = *(const float4*)&Wh[(size_t)i * 256 + lane * 4];
  float4 a1 = *(const float4*)&a[lane * 4];
  float4 a2 = *(const float4*)&a[256 + lane * 4];
  float s1 = wv.x * a1.x + wv.y * a1.y + wv.z * a1.z + wv.w * a1.w;
  float s2 = wv.x * a2.x + wv.y * a2.y + wv.z * a2.z + wv.w * a2.w;
#pragma unroll
  for (int off = 32; off; off >>= 1) { s1 += __shfl_xor(s1, off); s2 += __shfl_xor(s2, off); }
  // transposed bf16 copy: WhT[c][i]
  const float wvv[4] = {wv.x, wv.y, wv.z, wv.w};
#pragma unroll
  for (int c = 0; c < 4; c++)
    WhT[(size_t)(lane * 4 + c) * 8192 + i] = f2bf(wvv[c]);
  if (lane == 0) {
    f1[i] = s1; f2[i] = s2;
    float u = __expf(s2), v = __expf(ALPHA * s2);
    uvpack[i] = (unsigned)f2bf(u) | ((unsigned)f2bf(v) << 16);
  }
}

// ---------------- Kernel Bmax: F2max = max_j f2[j] --------------------------
__global__ __launch_bounds__(256) void f2max_k(const float* __restrict__ f2,
                                               float* __restrict__ f2maxp) {
  __shared__ float red[256];
  const int t = threadIdx.x;
  float m = -1e30f;
  for (int c = 0; c < 32; c++) m = fmaxf(m, f2[c * 256 + t]);
  red[t] = m;
  __syncthreads();
  for (int s = 128; s; s >>= 1) {
    if (t < s) red[t] = fmaxf(red[t], red[t + s]);
    __syncthreads();
  }
  if (t == 0) f2maxp[0] = red[0];
}

// ---------------- Kernel Z: zero accP (8 MB) + lP (32 KB) -------------------
// grid 2056: blocks [0,2048) zero accP, [2048,2056) zero lP.
__global__ __launch_bounds__(256) void zerok(float* __restrict__ accP,
                                             float* __restrict__ lP) {
  const int b = blockIdx.x, t = threadIdx.x;
  float4 z = {0.f, 0.f, 0.f, 0.f};
  if (b < 2048) {
    *(float4*)&accP[((size_t)b * 256 + t) * 4] = z;
  } else {
    *(float4*)&lP[((size_t)(b - 2048) * 256 + t) * 4] = z;
  }
}

// ---------------- Kernel C: fused masked-softmax @ Wh (the big one) ---------
// Wave-autonomous rewrite: NO barriers, NO LDS.
// Each wave owns a 32-row strip x all 256 output cols (8 acc tiles).
// The weight->lane assignment matches the MFMA 32x32x16 A-fragment map
// (row = lane&31, k = (lane>>5)*8 + idx), so the P tile is built entirely
// in-register. j is split 8 ways; partials combined via fp32 atomicAdd.
// grid 512 = 64 row-groups (128 rows: 4 waves x 32) x 8 j-splits.
// bid&7 = j-split: round-robin XCD assignment pins one 512KB WhT slice
// (plus its uvpack slice) per XCD L2.
__global__ __launch_bounds__(256, 2) void attn_main(const int* __restrict__ adj,
                                                    const float* __restrict__ f1,
                                                    const unsigned* __restrict__ uvpack,
                                                    const unsigned short* __restrict__ WhT,
                                                    const float* __restrict__ f2maxp,
                                                    float* __restrict__ accP,
                                                    float* __restrict__ lP) {
  const int t = threadIdx.x;
  const int wave = t >> 6, lane = t & 63;
  const int bid = blockIdx.x;
  const int js = bid & 7;          // j-split index (== XCD for round-robin)
  const int rg = bid >> 3;         // row-group 0..63
  const int r0 = rg * 128 + wave * 32;
  const int jbase = js * 1024;
  const int am = lane & 31, asel = lane >> 5;
  const int row = r0 + am;
  const int joff = asel * 8;       // k-offset of this lane's A-fragment slots

  const float F2max = f2maxp[0];
  const float f1v = f1[row];
  const float x = f1v + F2max;
  const float M = x > 0.f ? x : ALPHA * x;   // analytic per-row max bound
  const float Ai = __expf(f1v - M);
  const float Bi = __expf(ALPHA * f1v - M);
  const float Ui = __expf(-f1v);             // u_j > Ui  <=>  f1_i + f2_j > 0

  f32x16 acc[8] = {};

  // per-lane streams: 8 adj ints + 8 uv words per 16-j step, exactly the
  // j-slots of this lane's A fragment. adj lines are 64B-aligned and fully
  // consumed (lane covers j..j+7; its pair lane^32 covers j+8..j+15).
  const int* adjp = adj + (size_t)row * 8192 + jbase + joff;
  const unsigned* uvp = uvpack + jbase + joff;
  const unsigned short* wtp = WhT + (size_t)am * 8192 + jbase + joff;

  float lpriv = 0.f;
  int4 adv0 = *(const int4*)adjp;            // software pipeline: 1 iter ahead
  int4 adv1 = *(const int4*)(adjp + 4);
  uint4 uvv0 = *(const uint4*)uvp;
  uint4 uvv1 = *(const uint4*)(uvp + 4);

#pragma unroll 1
  for (int s = 0; s < 64; s++) {             // 64 x 16 j = 1024-j span
    const int4 a0 = adv0, a1 = adv1;
    const uint4 u0 = uvv0, u1 = uvv1;
    if (s < 63) {
      adv0 = *(const int4*)(adjp + (s + 1) * 16);
      adv1 = *(const int4*)(adjp + (s + 1) * 16 + 4);
      uvv0 = *(const uint4*)(uvp + (s + 1) * 16);
      uvv1 = *(const uint4*)(uvp + (s + 1) * 16 + 4);
    }
    // B fragments for all 8 col-tiles (L2-resident WhT, 16B contiguous/lane)
    short8 bf[8];
#pragma unroll
    for (int ct = 0; ct < 8; ct++)
      bf[ct] = *(const short8*)(wtp + (size_t)ct * (32 * 8192) + s * 16);

    const int ad[8] = {a0.x, a0.y, a0.z, a0.w, a1.x, a1.y, a1.z, a1.w};
    const unsigned uu[8] = {u0.x, u0.y, u0.z, u0.w, u1.x, u1.y, u1.z, u1.w};
    float w[8];
#pragma unroll
    for (int jj = 0; jj < 8; jj++) {
      float u = bf2f((unsigned short)(uu[jj] & 0xFFFFu));
      float v = bf2f((unsigned short)(uu[jj] >> 16));
      float wv = (u > Ui) ? Ai * u : Bi * v;   // exp(leaky(f1+f2)-M), factorized
      wv = (ad[jj] > 0) ? wv : 0.f;
      w[jj] = wv;
    }
    lpriv += ((w[0] + w[1]) + (w[2] + w[3])) + ((w[4] + w[5]) + (w[6] + w[7]));
    short8 af;
#pragma unroll
    for (int jj = 0; jj < 8; jj++) af[jj] = (short)f2bf(w[jj]);

#pragma unroll
    for (int ct = 0; ct < 8; ct++)
      acc[ct] = __builtin_amdgcn_mfma_f32_32x32x16_bf16(af, bf[ct], acc[ct], 0, 0, 0);
  }

  // row-sum: lane and lane^32 hold the two j-halves of the same row
  lpriv += __shfl_xor(lpriv, 32);
  if (asel == 0) atomicAdd(&lP[row], lpriv);

  // combine partials across the 8 j-splits (same M_i everywhere, no rescale)
#pragma unroll
  for (int ct = 0; ct < 8; ct++) {
#pragma unroll
    for (int reg = 0; reg < 16; reg++) {
      const int rowl = (reg & 3) + 8 * (reg >> 2) + 4 * asel;  // verified C/D map
      atomicAdd(&accP[(size_t)(r0 + rowl) * 256 + ct * 32 + am], acc[ct][reg]);
    }
  }
}

// ---------------- Kernel D: normalize + ELU ---------------------------------
__global__ __launch_bounds__(256) void combine(const float* __restrict__ accP,
                                               const float* __restrict__ lP,
                                               float* __restrict__ out) {
  const int idx = (blockIdx.x * 256 + threadIdx.x) * 4;
  const int row = idx >> 8;
  float4 a0 = *(const float4*)&accP[idx];
  float l = lP[row];
  float inv = 1.0f / fmaxf(l, 1e-30f);
  float vv[4] = {a0.x * inv, a0.y * inv, a0.z * inv, a0.w * inv};
  float4 o;
  o.x = vv[0] > 0.f ? vv[0] : __expf(vv[0]) - 1.f;
  o.y = vv[1] > 0.f ? vv[1] : __expf(vv[1]) - 1.f;
  o.z = vv[2] > 0.f ? vv[2] : __expf(vv[2]) - 1.f;
  o.w = vv[3] > 0.f ? vv[3] : __expf(vv[3]) - 1.f;
  *(float4*)&out[idx] = o;
}

extern "C" void kernel_launch(void* const* d_in, const int* in_sizes, int n_in,
                              void* d_out, int out_size, void* d_ws, size_t ws_size,
                              hipStream_t stream) {
  const float* h  = (const float*)d_in[0];
  const int* adj  = (const int*)d_in[1];
  const float* W  = (const float*)d_in[2];
  const float* a  = (const float*)d_in[3];
  float* out = (float*)d_out;
  char* ws = (char*)d_ws;

  // ws layout (aliased, same offsets as before):
  //  [0, 8M):    Wh fp32 (kernels A/B) THEN accP fp32 (zerok onward)
  //  [16M, 20M): WhT bf16 (4 MB)
  //  [20M ...):  f1 (32K), f2 (32K), uvpack (32K), f2max (128B), lP (32K)
  float* Wh            = (float*)ws;
  float* accP          = (float*)ws;
  unsigned short* WhT  = (unsigned short*)(ws + (size_t)(16u << 20));
  float* f1            = (float*)(ws + (size_t)(20u << 20));
  float* f2            = (float*)(ws + (size_t)(20u << 20) + (32u << 10));
  unsigned* uvpack     = (unsigned*)(ws + (size_t)(20u << 20) + (64u << 10));
  float* f2maxp        = (float*)(ws + (size_t)(20u << 20) + (96u << 10));
  float* lP            = (float*)(ws + (size_t)(20u << 20) + (97u << 10));

  gemm1<<<256, 256, 0, stream>>>(h, W, Wh);
  rowstats<<<2048, 256, 0, stream>>>(Wh, a, f1, f2, uvpack, WhT);
  f2max_k<<<1, 256, 0, stream>>>(f2, f2maxp);
  zerok<<<2056, 256, 0, stream>>>(accP, lP);      // Wh dead after rowstats
  attn_main<<<512, 256, 0, stream>>>(adj, f1, uvpack, WhT, f2maxp, accP, lP);
  combine<<<2048, 256, 0, stream>>>(accP, lP, out);
}

// Round 2
// 570.363 us; speedup vs baseline: 1.0700x; 1.0700x over previous
//
#include <hip/hip_runtime.h>
#include <cstdint>
#include <cstddef>

#define ALPHA 0.2f
// N=8192, Fin=512, Fout=256 hard-coded per problem instance.

typedef __attribute__((ext_vector_type(8)))  short short8;   // 8 bf16 (4 VGPRs)
typedef __attribute__((ext_vector_type(16))) float f32x16;   // 32x32 MFMA acc

static __device__ __forceinline__ unsigned short f2bf(float x) {
  union { float f; unsigned u; } c; c.f = x;
  unsigned u = c.u;
  unsigned r = (u + 0x7FFFu + ((u >> 16) & 1u)) >> 16;  // RNE
  return (unsigned short)r;
}
static __device__ __forceinline__ float bf2f(unsigned short b) {
  union { unsigned u; float f; } c; c.u = ((unsigned)b) << 16;
  return c.f;
}

// ---------------- Kernel A: Wh = h @ W  (fp32, 8192x512 * 512x256) ----------
// BM=128, BN=64, BK=32, 256 threads, 8x4 per thread. grid 64*4=256 blocks.
__global__ __launch_bounds__(256, 2) void gemm1(const float* __restrict__ h,
                                                const float* __restrict__ W,
                                                float* __restrict__ Wh) {
  __shared__ float As[32][132];  // [k][m], padded
  __shared__ float Bs[32][64];   // [k][n]
  const int t = threadIdx.x;
  const int bid = blockIdx.x;
  const int nb = bid & 3, mb = bid >> 2;
  const int m0 = mb * 128, n0 = nb * 64;
  const int ty = t >> 4, tx = t & 15;
  float acc[8][4];
#pragma unroll
  for (int i = 0; i < 8; i++)
#pragma unroll
    for (int j = 0; j < 4; j++) acc[i][j] = 0.f;

  for (int k0 = 0; k0 < 512; k0 += 32) {
#pragma unroll
    for (int c = 0; c < 4; c++) {                 // stage A with transpose
      int m = c * 32 + (t >> 3);
      int kq = (t & 7) * 4;
      float4 v = *(const float4*)&h[(size_t)(m0 + m) * 512 + k0 + kq];
      As[kq + 0][m] = v.x; As[kq + 1][m] = v.y;
      As[kq + 2][m] = v.z; As[kq + 3][m] = v.w;
    }
#pragma unroll
    for (int c = 0; c < 2; c++) {                 // stage B
      int k = c * 16 + (t >> 4);
      int n = (t & 15) * 4;
      *(float4*)&Bs[k][n] = *(const float4*)&W[(size_t)(k0 + k) * 256 + n0 + n];
    }
    __syncthreads();
#pragma unroll
    for (int k = 0; k < 32; k++) {
      float4 a0 = *(float4*)&As[k][ty * 8];
      float4 a1 = *(float4*)&As[k][ty * 8 + 4];
      float4 b  = *(float4*)&Bs[k][tx * 4];
      float av[8] = {a0.x, a0.y, a0.z, a0.w, a1.x, a1.y, a1.z, a1.w};
      float bv[4] = {b.x, b.y, b.z, b.w};
#pragma unroll
      for (int i = 0; i < 8; i++)
#pragma unroll
        for (int j = 0; j < 4; j++) acc[i][j] = fmaf(av[i], bv[j], acc[i][j]);
    }
    __syncthreads();
  }
#pragma unroll
  for (int i = 0; i < 8; i++) {
    float4 v = {acc[i][0], acc[i][1], acc[i][2], acc[i][3]};
    *(float4*)&Wh[(size_t)(m0 + ty * 8 + i) * 256 + n0 + tx * 4] = v;
  }
}

// ------------- Kernel B: per-row f1,f2 and u/v pack (no more WhT scatter) ---
// one wave per row; grid 2048 x 256
__global__ __launch_bounds__(256) void rowstats(const float* __restrict__ Wh,
                                                const float* __restrict__ a,
                                                float* __restrict__ f1,
                                                float* __restrict__ f2,
                                                unsigned* __restrict__ uvpack) {
  const int t = threadIdx.x;
  const int w = t >> 6, lane = t & 63;
  const int i = blockIdx.x * 4 + w;
  float4 wv = *(const float4*)&Wh[(size_t)i * 256 + lane * 4];
  float4 a1 = *(const float4*)&a[lane * 4];
  float4 a2 = *(const float4*)&a[256 + lane * 4];
  float s1 = wv.x * a1.x + wv.y * a1.y + wv.z * a1.z + wv.w * a1.w;
  float s2 = wv.x * a2.x + wv.y * a2.y + wv.z * a2.z + wv.w * a2.w;
#pragma unroll
  for (int off = 32; off; off >>= 1) { s1 += __shfl_xor(s1, off); s2 += __shfl_xor(s2, off); }
  if (lane == 0) {
    f1[i] = s1; f2[i] = s2;
    float u = __expf(s2), v = __expf(ALPHA * s2);
    uvpack[i] = (unsigned)f2bf(u) | ((unsigned)f2bf(v) << 16);
  }
}

// ------------- Kernel B2: LDS-tiled transpose Wh fp32 -> WhT bf16 -----------
// grid 512 = 128 i-tiles (64 i) x 4 c-tiles (64 c). Coalesced both sides.
__global__ __launch_bounds__(256) void wtrans(const float* __restrict__ Wh,
                                              unsigned short* __restrict__ WhT) {
  __shared__ unsigned short T[64][80];   // 80-short stride: 160B (16B mult)
  const int t = threadIdx.x;
  const int bi = blockIdx.x & 127;
  const int bc = blockIdx.x >> 7;
  const int i0 = bi * 64, c0 = bc * 64;
  {
    const int il = t >> 2, cq = (t & 3) * 16;
#pragma unroll
    for (int k = 0; k < 4; ++k) {
      float4 v = *(const float4*)&Wh[(size_t)(i0 + il) * 256 + c0 + cq + k * 4];
      T[cq + k * 4 + 0][il] = f2bf(v.x);
      T[cq + k * 4 + 1][il] = f2bf(v.y);
      T[cq + k * 4 + 2][il] = f2bf(v.z);
      T[cq + k * 4 + 3][il] = f2bf(v.w);
    }
  }
  __syncthreads();
  {
    const int cl = t >> 2, iq = (t & 3) * 16;
    *(uint4*)&WhT[(size_t)(c0 + cl) * 8192 + i0 + iq]     = *(const uint4*)&T[cl][iq];
    *(uint4*)&WhT[(size_t)(c0 + cl) * 8192 + i0 + iq + 8] = *(const uint4*)&T[cl][iq + 8];
  }
}

// ---------------- Kernel Bmax: F2max = max_j f2[j] --------------------------
__global__ __launch_bounds__(256) void f2max_k(const float* __restrict__ f2,
                                               float* __restrict__ f2maxp) {
  __shared__ float red[256];
  const int t = threadIdx.x;
  float m = -1e30f;
  for (int c = 0; c < 32; c++) m = fmaxf(m, f2[c * 256 + t]);
  red[t] = m;
  __syncthreads();
  for (int s = 128; s; s >>= 1) {
    if (t < s) red[t] = fmaxf(red[t], red[t + s]);
    __syncthreads();
  }
  if (t == 0) f2maxp[0] = red[0];
}

// ---------------- Kernel C: fused masked-softmax @ Wh (the big one) ---------
// Block = 32 rows x FULL j-range. 4 waves = 4 j-quarters of 2048.
// Wave-autonomous in-register P (no barriers in main loop); single in-LDS
// combine at the end; normalize+ELU+store out directly. No atomics, no
// partial buffers, no zero/combine kernels. grid 256 = 1 block/CU
// (grid-limited occupancy -> register budget per wave is ~512: deep prefetch).
// adj/uv prefetched 2 steps ahead; B-fragments double-buffered 1 step ahead.
#define ATTN_PHASE(S_CUR, A0, A1, U0, U1, BF_CUR, BF_NXT)                        \
  {                                                                              \
    const int ad_[8] = {A0.x, A0.y, A0.z, A0.w, A1.x, A1.y, A1.z, A1.w};         \
    const unsigned uu_[8] = {U0.x, U0.y, U0.z, U0.w, U1.x, U1.y, U1.z, U1.w};    \
    float w_[8];                                                                 \
    _Pragma("unroll")                                                            \
    for (int jj = 0; jj < 8; jj++) {                                             \
      float u = bf2f((unsigned short)(uu_[jj] & 0xFFFFu));                       \
      float v = bf2f((unsigned short)(uu_[jj] >> 16));                           \
      float wv = (u > Ui) ? Ai * u : Bi * v;                                     \
      w_[jj] = (ad_[jj] > 0) ? wv : 0.f;                                         \
    }                                                                            \
    lpriv += ((w_[0] + w_[1]) + (w_[2] + w_[3])) + ((w_[4] + w_[5]) + (w_[6] + w_[7])); \
    union { uint4 q; short8 s; } af_;                                            \
    asm("v_cvt_pk_bf16_f32 %0, %1, %2" : "=v"(af_.q.x) : "v"(w_[0]), "v"(w_[1]));\
    asm("v_cvt_pk_bf16_f32 %0, %1, %2" : "=v"(af_.q.y) : "v"(w_[2]), "v"(w_[3]));\
    asm("v_cvt_pk_bf16_f32 %0, %1, %2" : "=v"(af_.q.z) : "v"(w_[4]), "v"(w_[5]));\
    asm("v_cvt_pk_bf16_f32 %0, %1, %2" : "=v"(af_.q.w) : "v"(w_[6]), "v"(w_[7]));\
    const int sRe_ = (S_CUR) + 2;                                                \
    if (sRe_ < 128) {                                                            \
      A0 = *(const int4*)(adjp + sRe_ * 16);                                     \
      A1 = *(const int4*)(adjp + sRe_ * 16 + 4);                                 \
      U0 = *(const uint4*)(uvp + sRe_ * 16);                                     \
      U1 = *(const uint4*)(uvp + sRe_ * 16 + 4);                                 \
    }                                                                            \
    const int sN_ = (S_CUR) + 1;                                                 \
    if (sN_ < 128) {                                                             \
      _Pragma("unroll")                                                          \
      for (int ct = 0; ct < 8; ct++)                                             \
        BF_NXT[ct] = *(const short8*)(wtp + (size_t)ct * (32 * 8192) + sN_ * 16);\
    }                                                                            \
    _Pragma("unroll")                                                            \
    for (int ct = 0; ct < 8; ct++)                                               \
      acc[ct] = __builtin_amdgcn_mfma_f32_32x32x16_bf16(af_.s, BF_CUR[ct], acc[ct], 0, 0, 0); \
  }

__global__ __launch_bounds__(256, 1) void attn_main(const int* __restrict__ adj,
                                                    const float* __restrict__ f1,
                                                    const unsigned* __restrict__ uvpack,
                                                    const unsigned short* __restrict__ WhT,
                                                    const float* __restrict__ f2maxp,
                                                    float* __restrict__ out) {
  __shared__ float red[4][32][260];   // 260-float stride breaks bank alias; 133 KB
  __shared__ float lsum[4][32];
  const int t = threadIdx.x;
  const int wave = t >> 6, lane = t & 63;
  const int am = lane & 31, asel = lane >> 5;
  const int r0 = blockIdx.x * 32;
  const int row = r0 + am;
  const int jq = wave * 2048;           // wave's j-quarter
  const int joff = jq + asel * 8;

  const float F2max = f2maxp[0];
  const float f1v = f1[row];
  const float x = f1v + F2max;
  const float M = x > 0.f ? x : ALPHA * x;   // analytic per-row max bound
  const float Ai = __expf(f1v - M);
  const float Bi = __expf(ALPHA * f1v - M);
  const float Ui = __expf(-f1v);             // u_j > Ui  <=>  f1_i + f2_j > 0

  f32x16 acc[8] = {};
  const int* adjp = adj + (size_t)row * 8192 + joff;
  const unsigned* uvp = uvpack + joff;
  const unsigned short* wtp = WhT + (size_t)am * 8192 + joff;

  // prologue: steps 0 (A-set) and 1 (B-set) in flight; bfA = step 0
  int4 aA0 = *(const int4*)(adjp);
  int4 aA1 = *(const int4*)(adjp + 4);
  uint4 uA0 = *(const uint4*)(uvp);
  uint4 uA1 = *(const uint4*)(uvp + 4);
  int4 aB0 = *(const int4*)(adjp + 16);
  int4 aB1 = *(const int4*)(adjp + 20);
  uint4 uB0 = *(const uint4*)(uvp + 16);
  uint4 uB1 = *(const uint4*)(uvp + 20);
  short8 bfA[8], bfB[8];
#pragma unroll
  for (int ct = 0; ct < 8; ct++)
    bfA[ct] = *(const short8*)(wtp + (size_t)ct * (32 * 8192));
  float lpriv = 0.f;

#pragma unroll 1
  for (int it = 0; it < 64; ++it) {
    ATTN_PHASE(2 * it,     aA0, aA1, uA0, uA1, bfA, bfB);
    ATTN_PHASE(2 * it + 1, aB0, aB1, uB0, uB1, bfB, bfA);
  }

  // dump partials to LDS (each wave its own slice)
#pragma unroll
  for (int ct = 0; ct < 8; ct++) {
#pragma unroll
    for (int reg = 0; reg < 16; reg++) {
      const int rowl = (reg & 3) + 8 * (reg >> 2) + 4 * asel;  // verified C/D map
      red[wave][rowl][ct * 32 + am] = acc[ct][reg];
    }
  }
  lpriv += __shfl_xor(lpriv, 32);      // combine asel halves of row am
  if (asel == 0) lsum[wave][am] = lpriv;
  __syncthreads();

  // combine 4 j-quarters (same M per row everywhere -> plain add),
  // normalize, ELU, store out. thread t: row rr=t>>3, col chunk (t&7)*32.
  const int rr = t >> 3, cb = (t & 7) * 32;
  const float l = lsum[0][rr] + lsum[1][rr] + lsum[2][rr] + lsum[3][rr];
  const float inv = 1.0f / fmaxf(l, 1e-30f);
#pragma unroll
  for (int cc = 0; cc < 32; cc += 4) {
    float4 v;
    v.x = red[0][rr][cb + cc + 0] + red[1][rr][cb + cc + 0] + red[2][rr][cb + cc + 0] + red[3][rr][cb + cc + 0];
    v.y = red[0][rr][cb + cc + 1] + red[1][rr][cb + cc + 1] + red[2][rr][cb + cc + 1] + red[3][rr][cb + cc + 1];
    v.z = red[0][rr][cb + cc + 2] + red[1][rr][cb + cc + 2] + red[2][rr][cb + cc + 2] + red[3][rr][cb + cc + 2];
    v.w = red[0][rr][cb + cc + 3] + red[1][rr][cb + cc + 3] + red[2][rr][cb + cc + 3] + red[3][rr][cb + cc + 3];
    v.x *= inv; v.y *= inv; v.z *= inv; v.w *= inv;
    float4 o;
    o.x = v.x > 0.f ? v.x : __expf(v.x) - 1.f;
    o.y = v.y > 0.f ? v.y : __expf(v.y) - 1.f;
    o.z = v.z > 0.f ? v.z : __expf(v.z) - 1.f;
    o.w = v.w > 0.f ? v.w : __expf(v.w) - 1.f;
    *(float4*)&out[(size_t)(r0 + rr) * 256 + cb + cc] = o;
  }
}

extern "C" void kernel_launch(void* const* d_in, const int* in_sizes, int n_in,
                              void* d_out, int out_size, void* d_ws, size_t ws_size,
                              hipStream_t stream) {
  const float* h  = (const float*)d_in[0];
  const int* adj  = (const int*)d_in[1];
  const float* W  = (const float*)d_in[2];
  const float* a  = (const float*)d_in[3];
  float* out = (float*)d_out;
  char* ws = (char*)d_ws;

  // ws layout:
  //  [0, 8M):    Wh fp32
  //  [16M, 20M): WhT bf16 (4 MB)
  //  [20M ...):  f1 (32K), f2 (32K), uvpack (32K), f2max (128B)
  float* Wh            = (float*)ws;
  unsigned short* WhT  = (unsigned short*)(ws + (size_t)(16u << 20));
  float* f1            = (float*)(ws + (size_t)(20u << 20));
  float* f2            = (float*)(ws + (size_t)(20u << 20) + (32u << 10));
  unsigned* uvpack     = (unsigned*)(ws + (size_t)(20u << 20) + (64u << 10));
  float* f2maxp        = (float*)(ws + (size_t)(20u << 20) + (96u << 10));

  gemm1<<<256, 256, 0, stream>>>(h, W, Wh);
  rowstats<<<2048, 256, 0, stream>>>(Wh, a, f1, f2, uvpack);
  wtrans<<<512, 256, 0, stream>>>(Wh, WhT);
  f2max_k<<<1, 256, 0, stream>>>(f2, f2maxp);
  attn_main<<<256, 256, 0, stream>>>(adj, f1, uvpack, WhT, f2maxp, out);
}

// Round 3
// 548.913 us; speedup vs baseline: 1.1118x; 1.0391x over previous
//
#include <hip/hip_runtime.h>
#include <cstdint>
#include <cstddef>

#define ALPHA 0.2f
// N=8192, Fin=512, Fout=256 hard-coded per problem instance.

typedef __attribute__((ext_vector_type(8)))  short short8;   // 8 bf16 (4 VGPRs)
typedef __attribute__((ext_vector_type(16))) float f32x16;   // 32x32 MFMA acc

static __device__ __forceinline__ unsigned short f2bf(float x) {
  union { float f; unsigned u; } c; c.f = x;
  unsigned u = c.u;
  unsigned r = (u + 0x7FFFu + ((u >> 16) & 1u)) >> 16;  // RNE
  return (unsigned short)r;
}

// ---------------- Kernel A: Wh = h @ W  (fp32, 8192x512 * 512x256) ----------
// Retiled: 512 threads (8 waves -> 2 waves/SIMD), acc 4x4/thread.
// Same k-accumulation order as before -> bit-identical Wh.
__global__ __launch_bounds__(512) void gemm1(const float* __restrict__ h,
                                             const float* __restrict__ W,
                                             float* __restrict__ Wh) {
  __shared__ float As[32][132];  // [k][m], padded
  __shared__ float Bs[32][64];   // [k][n]
  const int t = threadIdx.x;
  const int bid = blockIdx.x;
  const int nb = bid & 3, mb = bid >> 2;
  const int m0 = mb * 128, n0 = nb * 64;
  const int ty = t >> 4, tx = t & 15;   // rows ty*4.., cols tx*4..
  float acc[4][4];
#pragma unroll
  for (int i = 0; i < 4; i++)
#pragma unroll
    for (int j = 0; j < 4; j++) acc[i][j] = 0.f;

  for (int k0 = 0; k0 < 512; k0 += 32) {
#pragma unroll
    for (int c = 0; c < 2; c++) {                 // stage A with transpose
      int m = c * 64 + (t >> 3);
      int kq = (t & 7) * 4;
      float4 v = *(const float4*)&h[(size_t)(m0 + m) * 512 + k0 + kq];
      As[kq + 0][m] = v.x; As[kq + 1][m] = v.y;
      As[kq + 2][m] = v.z; As[kq + 3][m] = v.w;
    }
    {                                             // stage B
      int k = t >> 4;
      int n = (t & 15) * 4;
      *(float4*)&Bs[k][n] = *(const float4*)&W[(size_t)(k0 + k) * 256 + n0 + n];
    }
    __syncthreads();
#pragma unroll
    for (int k = 0; k < 32; k++) {
      float4 a = *(float4*)&As[k][ty * 4];
      float4 b = *(float4*)&Bs[k][tx * 4];
      float av[4] = {a.x, a.y, a.z, a.w};
      float bv[4] = {b.x, b.y, b.z, b.w};
#pragma unroll
      for (int i = 0; i < 4; i++)
#pragma unroll
        for (int j = 0; j < 4; j++) acc[i][j] = fmaf(av[i], bv[j], acc[i][j]);
    }
    __syncthreads();
  }
#pragma unroll
  for (int i = 0; i < 4; i++) {
    float4 v = {acc[i][0], acc[i][1], acc[i][2], acc[i][3]};
    *(float4*)&Wh[(size_t)(m0 + ty * 4 + i) * 256 + n0 + tx * 4] = v;
  }
}

// ------------- Kernel B: per-row f1,f2 and u/v pack -------------------------
__global__ __launch_bounds__(256) void rowstats(const float* __restrict__ Wh,
                                                const float* __restrict__ a,
                                                float* __restrict__ f1,
                                                float* __restrict__ f2,
                                                unsigned* __restrict__ uvpack) {
  const int t = threadIdx.x;
  const int w = t >> 6, lane = t & 63;
  const int i = blockIdx.x * 4 + w;
  float4 wv = *(const float4*)&Wh[(size_t)i * 256 + lane * 4];
  float4 a1 = *(const float4*)&a[lane * 4];
  float4 a2 = *(const float4*)&a[256 + lane * 4];
  float s1 = wv.x * a1.x + wv.y * a1.y + wv.z * a1.z + wv.w * a1.w;
  float s2 = wv.x * a2.x + wv.y * a2.y + wv.z * a2.z + wv.w * a2.w;
#pragma unroll
  for (int off = 32; off; off >>= 1) { s1 += __shfl_xor(s1, off); s2 += __shfl_xor(s2, off); }
  if (lane == 0) {
    f1[i] = s1; f2[i] = s2;
    float u = __expf(s2), v = __expf(ALPHA * s2);
    uvpack[i] = (unsigned)f2bf(u) | ((unsigned)f2bf(v) << 16);
  }
}

// ------------- Kernel B2: LDS-tiled transpose Wh fp32 -> WhT bf16 -----------
__global__ __launch_bounds__(256) void wtrans(const float* __restrict__ Wh,
                                              unsigned short* __restrict__ WhT) {
  __shared__ unsigned short T[64][80];   // 80-short stride
  const int t = threadIdx.x;
  const int bi = blockIdx.x & 127;
  const int bc = blockIdx.x >> 7;
  const int i0 = bi * 64, c0 = bc * 64;
  {
    const int il = t >> 2, cq = (t & 3) * 16;
#pragma unroll
    for (int k = 0; k < 4; ++k) {
      float4 v = *(const float4*)&Wh[(size_t)(i0 + il) * 256 + c0 + cq + k * 4];
      T[cq + k * 4 + 0][il] = f2bf(v.x);
      T[cq + k * 4 + 1][il] = f2bf(v.y);
      T[cq + k * 4 + 2][il] = f2bf(v.z);
      T[cq + k * 4 + 3][il] = f2bf(v.w);
    }
  }
  __syncthreads();
  {
    const int cl = t >> 2, iq = (t & 3) * 16;
    *(uint4*)&WhT[(size_t)(c0 + cl) * 8192 + i0 + iq]     = *(const uint4*)&T[cl][iq];
    *(uint4*)&WhT[(size_t)(c0 + cl) * 8192 + i0 + iq + 8] = *(const uint4*)&T[cl][iq + 8];
  }
}

// ---------------- Kernel Bmax: F2max = max_j f2[j] --------------------------
__global__ __launch_bounds__(256) void f2max_k(const float* __restrict__ f2,
                                               float* __restrict__ f2maxp) {
  __shared__ float red[256];
  const int t = threadIdx.x;
  float m = -1e30f;
  for (int c = 0; c < 32; c++) m = fmaxf(m, f2[c * 256 + t]);
  red[t] = m;
  __syncthreads();
  for (int s = 128; s; s >>= 1) {
    if (t < s) red[t] = fmaxf(red[t], red[t + s]);
    __syncthreads();
  }
  if (t == 0) f2maxp[0] = red[0];
}

// ---------------- Kernel M: pack adj>0 into a bitmask (8 MB) ----------------
// mask[row][it] (uint64): bit b = adj[row][it*64+b] > 0  (== __ballot order).
// Block = 4 rows (one/wave), full j. Streaming: 2048 blocks = 32 waves/CU.
__global__ __launch_bounds__(256) void maskpack(const int* __restrict__ adj,
                                                unsigned long long* __restrict__ mask) {
  __shared__ unsigned long long mbuf[4][128];
  const int t = threadIdx.x, wave = t >> 6, lane = t & 63;
  const int row = blockIdx.x * 4 + wave;
  const int* ap = adj + (size_t)row * 8192 + lane;
#pragma unroll 1
  for (int it0 = 0; it0 < 128; it0 += 4) {
    int a0 = ap[(it0 + 0) * 64];
    int a1 = ap[(it0 + 1) * 64];
    int a2 = ap[(it0 + 2) * 64];
    int a3 = ap[(it0 + 3) * 64];
    unsigned long long b0 = __ballot(a0 > 0);
    unsigned long long b1 = __ballot(a1 > 0);
    unsigned long long b2 = __ballot(a2 > 0);
    unsigned long long b3 = __ballot(a3 > 0);
    if (lane == 0) {
      mbuf[wave][it0 + 0] = b0; mbuf[wave][it0 + 1] = b1;
      mbuf[wave][it0 + 2] = b2; mbuf[wave][it0 + 3] = b3;
    }
  }
  __syncthreads();
  // coalesced flush: 4 rows x 1KB, contiguous in mask
  uint4* dst = (uint4*)(mask + (size_t)blockIdx.x * 4 * 128);
  dst[t] = ((const uint4*)mbuf)[t];
}

// ---------------- Kernel C: fused masked-softmax @ Wh -----------------------
// Same wave-autonomous structure as before (32 rows x full j, 4 waves =
// 4 j-quarters, in-register P, in-LDS combine), but the HBM adj stream is
// replaced by the L2-resident bitmask: 1 uint2 per lane per 4 steps,
// prefetched a full group (4 steps) ahead. uv prefetched a group ahead;
// bf double-buffered 1 step ahead. grid 256 = 1 block/CU.
#define ATTN_SUB(KSUB, MWORD, UCA, UCB, BFC, BFN, SCUR)                          \
  {                                                                              \
    const unsigned mbyte_ = ((MWORD) >> (((KSUB) & 1) * 16 + aselsh)) & 0xFFu;   \
    const unsigned uu_[8] = {UCA.x, UCA.y, UCA.z, UCA.w, UCB.x, UCB.y, UCB.z, UCB.w}; \
    float w_[8];                                                                 \
    _Pragma("unroll")                                                            \
    for (int jj = 0; jj < 8; jj++) {                                             \
      union { unsigned u; float f; } cu_, cv_;                                   \
      cu_.u = uu_[jj] << 16;                                                     \
      cv_.u = uu_[jj] & 0xFFFF0000u;                                             \
      float wv_ = (cu_.f > Ui) ? Ai * cu_.f : Bi * cv_.f;                        \
      int ext_ = ((int)(mbyte_ << (31 - jj))) >> 31;   /* bit -> 0 / all-ones */ \
      union { float f; int i; } wu_; wu_.f = wv_; wu_.i &= ext_;                 \
      w_[jj] = wu_.f;                                                            \
    }                                                                            \
    lpriv += ((w_[0] + w_[1]) + (w_[2] + w_[3])) + ((w_[4] + w_[5]) + (w_[6] + w_[7])); \
    union { uint4 q; short8 s; } af_;                                            \
    asm("v_cvt_pk_bf16_f32 %0, %1, %2" : "=v"(af_.q.x) : "v"(w_[0]), "v"(w_[1]));\
    asm("v_cvt_pk_bf16_f32 %0, %1, %2" : "=v"(af_.q.y) : "v"(w_[2]), "v"(w_[3]));\
    asm("v_cvt_pk_bf16_f32 %0, %1, %2" : "=v"(af_.q.z) : "v"(w_[4]), "v"(w_[5]));\
    asm("v_cvt_pk_bf16_f32 %0, %1, %2" : "=v"(af_.q.w) : "v"(w_[6]), "v"(w_[7]));\
    const int sn_ = (SCUR) + 1 < 128 ? (SCUR) + 1 : 127;                         \
    _Pragma("unroll")                                                            \
    for (int ct = 0; ct < 8; ct++)                                               \
      BFN[ct] = *(const short8*)(wtp + (size_t)ct * (32 * 8192) + (size_t)sn_ * 16); \
    _Pragma("unroll")                                                            \
    for (int ct = 0; ct < 8; ct++)                                               \
      acc[ct] = __builtin_amdgcn_mfma_f32_32x32x16_bf16(af_.s, BFC[ct], acc[ct], 0, 0, 0); \
  }

#define ATTN_GROUP(G, UC, UN, MC, MN)                                            \
  {                                                                              \
    const int gn_ = (G) < 31 ? (G) + 1 : 31;                                     \
    MN = mp[gn_];                                                                \
    UN[0] = *(const uint4*)(uvp + gn_ * 64 + 0);                                 \
    UN[1] = *(const uint4*)(uvp + gn_ * 64 + 4);                                 \
    ATTN_SUB(0, MC.x, UC[0], UC[1], bfA, bfB, 4 * (G) + 0);                      \
    UN[2] = *(const uint4*)(uvp + gn_ * 64 + 16);                                \
    UN[3] = *(const uint4*)(uvp + gn_ * 64 + 20);                                \
    ATTN_SUB(1, MC.x, UC[2], UC[3], bfB, bfA, 4 * (G) + 1);                      \
    UN[4] = *(const uint4*)(uvp + gn_ * 64 + 32);                                \
    UN[5] = *(const uint4*)(uvp + gn_ * 64 + 36);                                \
    ATTN_SUB(2, MC.y, UC[4], UC[5], bfA, bfB, 4 * (G) + 2);                      \
    UN[6] = *(const uint4*)(uvp + gn_ * 64 + 48);                                \
    UN[7] = *(const uint4*)(uvp + gn_ * 64 + 52);                                \
    ATTN_SUB(3, MC.y, UC[6], UC[7], bfB, bfA, 4 * (G) + 3);                      \
  }

__global__ __launch_bounds__(256, 1) void attn_main(const unsigned long long* __restrict__ maskw,
                                                    const float* __restrict__ f1,
                                                    const unsigned* __restrict__ uvpack,
                                                    const unsigned short* __restrict__ WhT,
                                                    const float* __restrict__ f2maxp,
                                                    float* __restrict__ out) {
  __shared__ float red[4][32][260];   // 260-float stride breaks bank alias; 133 KB
  __shared__ float lsum[4][32];
  const int t = threadIdx.x;
  const int wave = t >> 6, lane = t & 63;
  const int am = lane & 31, asel = lane >> 5;
  const int aselsh = asel * 8;
  const int r0 = blockIdx.x * 32;
  const int row = r0 + am;
  const int jq = wave * 2048;           // wave's j-quarter

  const float F2max = f2maxp[0];
  const float f1v = f1[row];
  const float x = f1v + F2max;
  const float M = x > 0.f ? x : ALPHA * x;   // analytic per-row max bound
  const float Ai = __expf(f1v - M);
  const float Bi = __expf(ALPHA * f1v - M);
  const float Ui = __expf(-f1v);             // u_j > Ui  <=>  f1_i + f2_j > 0

  f32x16 acc[8] = {};
  // mask: uint2 view, 128 uint64/row; this wave starts at block it0 = wave*32
  const uint2* mp = (const uint2*)maskw + (size_t)row * 128 + wave * 32;
  const unsigned* uvp = uvpack + jq + aselsh;
  const unsigned short* wtp = WhT + (size_t)am * 8192 + jq + aselsh;

  // prologue: group 0 uv+mask, step-0 bf
  uint2 mg = mp[0], mgN;
  uint4 ug[8], ugN[8];
#pragma unroll
  for (int k = 0; k < 4; k++) {
    ug[2 * k]     = *(const uint4*)(uvp + k * 16);
    ug[2 * k + 1] = *(const uint4*)(uvp + k * 16 + 4);
  }
  short8 bfA[8], bfB[8];
#pragma unroll
  for (int ct = 0; ct < 8; ct++)
    bfA[ct] = *(const short8*)(wtp + (size_t)ct * (32 * 8192));
  float lpriv = 0.f;

#pragma unroll 1
  for (int gg = 0; gg < 16; ++gg) {
    ATTN_GROUP(2 * gg,     ug,  ugN, mg,  mgN);
    ATTN_GROUP(2 * gg + 1, ugN, ug,  mgN, mg);
  }

  // dump partials to LDS (each wave its own slice)
#pragma unroll
  for (int ct = 0; ct < 8; ct++) {
#pragma unroll
    for (int reg = 0; reg < 16; reg++) {
      const int rowl = (reg & 3) + 8 * (reg >> 2) + 4 * asel;  // verified C/D map
      red[wave][rowl][ct * 32 + am] = acc[ct][reg];
    }
  }
  lpriv += __shfl_xor(lpriv, 32);      // combine asel halves of row am
  if (asel == 0) lsum[wave][am] = lpriv;
  __syncthreads();

  // combine 4 j-quarters, normalize, ELU, store out.
  const int rr = t >> 3, cb = (t & 7) * 32;
  const float l = lsum[0][rr] + lsum[1][rr] + lsum[2][rr] + lsum[3][rr];
  const float inv = 1.0f / fmaxf(l, 1e-30f);
#pragma unroll
  for (int cc = 0; cc < 32; cc += 4) {
    float4 v;
    v.x = red[0][rr][cb + cc + 0] + red[1][rr][cb + cc + 0] + red[2][rr][cb + cc + 0] + red[3][rr][cb + cc + 0];
    v.y = red[0][rr][cb + cc + 1] + red[1][rr][cb + cc + 1] + red[2][rr][cb + cc + 1] + red[3][rr][cb + cc + 1];
    v.z = red[0][rr][cb + cc + 2] + red[1][rr][cb + cc + 2] + red[2][rr][cb + cc + 2] + red[3][rr][cb + cc + 2];
    v.w = red[0][rr][cb + cc + 3] + red[1][rr][cb + cc + 3] + red[2][rr][cb + cc + 3] + red[3][rr][cb + cc + 3];
    v.x *= inv; v.y *= inv; v.z *= inv; v.w *= inv;
    float4 o;
    o.x = v.x > 0.f ? v.x : __expf(v.x) - 1.f;
    o.y = v.y > 0.f ? v.y : __expf(v.y) - 1.f;
    o.z = v.z > 0.f ? v.z : __expf(v.z) - 1.f;
    o.w = v.w > 0.f ? v.w : __expf(v.w) - 1.f;
    *(float4*)&out[(size_t)(r0 + rr) * 256 + cb + cc] = o;
  }
}

extern "C" void kernel_launch(void* const* d_in, const int* in_sizes, int n_in,
                              void* d_out, int out_size, void* d_ws, size_t ws_size,
                              hipStream_t stream) {
  const float* h  = (const float*)d_in[0];
  const int* adj  = (const int*)d_in[1];
  const float* W  = (const float*)d_in[2];
  const float* a  = (const float*)d_in[3];
  float* out = (float*)d_out;
  char* ws = (char*)d_ws;

  // ws layout:
  //  [0, 8M):    Wh fp32
  //  [8M, 16M):  mask bits (8 MB)
  //  [16M, 20M): WhT bf16 (4 MB)
  //  [20M ...):  f1 (32K), f2 (32K), uvpack (32K), f2max (128B)
  float* Wh            = (float*)ws;
  unsigned long long* mask = (unsigned long long*)(ws + (size_t)(8u << 20));
  unsigned short* WhT  = (unsigned short*)(ws + (size_t)(16u << 20));
  float* f1            = (float*)(ws + (size_t)(20u << 20));
  float* f2            = (float*)(ws + (size_t)(20u << 20) + (32u << 10));
  unsigned* uvpack     = (unsigned*)(ws + (size_t)(20u << 20) + (64u << 10));
  float* f2maxp        = (float*)(ws + (size_t)(20u << 20) + (96u << 10));

  maskpack<<<2048, 256, 0, stream>>>(adj, mask);
  gemm1<<<256, 512, 0, stream>>>(h, W, Wh);
  rowstats<<<2048, 256, 0, stream>>>(Wh, a, f1, f2, uvpack);
  wtrans<<<512, 256, 0, stream>>>(Wh, WhT);
  f2max_k<<<1, 256, 0, stream>>>(f2, f2maxp);
  attn_main<<<256, 256, 0, stream>>>(mask, f1, uvpack, WhT, f2maxp, out);
}